// Round 8
// baseline (380.053 us; speedup 1.0000x reference)
//
#include <hip/hip_runtime.h>

// out[b,s,j] = sum_k x[b,s,k] * w_concat[inv_perm[j], k] + bias[j]
// INT8 path: weights exact in i8; x per-token quantized (sx = absmax/127).
// Round 7: same 4-phase 256x256 BK=128 schedule as round 6, with
//  (a) kk-OUTERMOST MFMA ordering (dependent acc reuse distance 8, no stalls),
//  (b) K-loop unrolled x2 with compile-time buffer parity,
//  (c) precomputed LDS read-base pointers (all ds_read = base + imm offset).

#define M_TOK 16384
#define N_O   4096
#define K_IN  4096
#define N8F   2048
#define NT    (K_IN / 128)   // 32 K-tiles of BK=128 i8 (128 B/row)

typedef __attribute__((ext_vector_type(4))) int i32x4;

__device__ __forceinline__ void gl_lds16(const void* g, void* l) {
  __builtin_amdgcn_global_load_lds(
      (const __attribute__((address_space(1))) unsigned int*)g,
      (__attribute__((address_space(3))) unsigned int*)l, 16, 0, 0);
}

__device__ __forceinline__ int clampq(float f) {
  int q = (int)rintf(f);
  return q > 127 ? 127 : (q < -127 ? -127 : q);
}

// ---- fused prep: blocks [0,N_O) pack weights to i8; blocks [N_O, N_O+M_TOK)
// ---- quantize one token each (absmax -> sx, xq). Row-major i8, 4096 B rows.
__global__ void prep_kernel(const float* __restrict__ x,
                            const int4* __restrict__ q8, const float* __restrict__ s8,
                            const int4* __restrict__ q4, const float* __restrict__ s4,
                            const int* __restrict__ inv,
                            char* __restrict__ Wq, float* __restrict__ scale,
                            float* __restrict__ sx, char* __restrict__ xq) {
  __shared__ float red[4];
  const int t = threadIdx.x;
  if (blockIdx.x < N_O) {
    const int j = blockIdx.x;
    const int c = inv[j];
    const int4* src; float s;
    if (c < N8F) { src = q8 + (size_t)c * (K_IN / 4);         s = s8[c]; }
    else         { src = q4 + (size_t)(c - N8F) * (K_IN / 4); s = s4[c - N8F]; }
    if (t == 0) scale[j] = s;
    unsigned dw[4];
#pragma unroll
    for (int i = 0; i < 4; ++i) {
      int4 v = src[t * 4 + i];
      dw[i] = (v.x & 255) | ((v.y & 255) << 8) | ((v.z & 255) << 16)
            | ((unsigned)(v.w & 255) << 24);
    }
    *(uint4*)(Wq + (size_t)j * K_IN + t * 16) = make_uint4(dw[0], dw[1], dw[2], dw[3]);
  } else {
    const int T = blockIdx.x - N_O;
    const float4* xr = (const float4*)(x + (size_t)T * K_IN);
    float4 v[4];
    float m = 0.f;
#pragma unroll
    for (int i = 0; i < 4; ++i) {
      v[i] = xr[t * 4 + i];
      m = fmaxf(m, fmaxf(fmaxf(fabsf(v[i].x), fabsf(v[i].y)),
                         fmaxf(fabsf(v[i].z), fabsf(v[i].w))));
    }
#pragma unroll
    for (int o = 32; o; o >>= 1) m = fmaxf(m, __shfl_xor(m, o));
    if ((t & 63) == 0) red[t >> 6] = m;
    __syncthreads();
    m = fmaxf(fmaxf(red[0], red[1]), fmaxf(red[2], red[3]));
    const float rq = m > 0.f ? 127.f / m : 0.f;
    if (t == 0) sx[T] = m * (1.f / 127.f);
    unsigned dw[4];
#pragma unroll
    for (int i = 0; i < 4; ++i) {
      int a0 = clampq(v[i].x * rq), a1 = clampq(v[i].y * rq);
      int a2 = clampq(v[i].z * rq), a3 = clampq(v[i].w * rq);
      dw[i] = (a0 & 255) | ((a1 & 255) << 8) | ((a2 & 255) << 16)
            | ((unsigned)(a3 & 255) << 24);
    }
    *(uint4*)(xq + (size_t)T * K_IN + t * 16) = make_uint4(dw[0], dw[1], dw[2], dw[3]);
  }
}

// ================= 256x256 i8 GEMM, BK=128, 4-phase schedule =================
// LDS map (bytes): buf*65536 + { A: half*16384 | B: 32768 + half*16384 }
// half = 128 rows x 128 B; swizzle: phys_colbyte = logical ^ ((row&7)<<4)

// kk-outermost MFMA cluster: 8 independent, then same accs again (distance 8).
#define CL8(ACCB, AF)                                                                   \
  __builtin_amdgcn_s_setprio(1);                                                        \
  _Pragma("unroll") for (int m_ = 0; m_ < 2; ++m_)                                      \
  _Pragma("unroll") for (int n_ = 0; n_ < 4; ++n_)                                      \
    acc[(ACCB) + m_][n_] = __builtin_amdgcn_mfma_i32_16x16x64_i8(                       \
        AF[m_][0], bfr[n_][0], acc[(ACCB) + m_][n_], 0, 0, 0);                          \
  _Pragma("unroll") for (int m_ = 0; m_ < 2; ++m_)                                      \
  _Pragma("unroll") for (int n_ = 0; n_ < 4; ++n_)                                      \
    acc[(ACCB) + m_][n_] = __builtin_amdgcn_mfma_i32_16x16x64_i8(                       \
        AF[m_][1], bfr[n_][1], acc[(ACCB) + m_][n_], 0, 0, 0);                          \
  __builtin_amdgcn_s_setprio(0);

// One K-tile; CUR is a literal 0/1 (compile-time buffer parity).
// rA/rB: LDS read bases (per parity, per kk-xor); aLb/bLb: LDS stage dest base
// for buffer CUR^1 / CUR; aG/bG: global stage bases (lane-swizzled).
#define KTBODY(CUR, kt)                                                                 \
  {                                                                                     \
    const char* rA  = (CUR) ? rA1 : rA0;                                                \
    const char* rAx = (CUR) ? rA1x : rA0x;                                              \
    const char* rB  = (CUR) ? rB1 : rB0;                                                \
    const char* rBx = (CUR) ? rB1x : rB0x;                                              \
    char* aDn = aL0 + ((CUR) ^ 1) * 65536;  /* stage dest: A of buf^1 */                \
    char* aDc = aL0 + (CUR) * 65536;        /* stage dest: A of cur  */                 \
    char* bDc = bL0 + (CUR) * 65536;        /* stage dest: B of cur  */                 \
    const int o1 = ((kt) + 1) << 7, o2 = ((kt) + 2) << 7;                               \
    /* ---- phase 1: read all B (8) + A mg0 (4); stage A(kt+1) h1 -> buf^1 */           \
    _Pragma("unroll") for (int n_ = 0; n_ < 4; ++n_) {                                  \
      bfr[n_][0] = *(const i32x4*)(rB + n_ * 2048);                                     \
      bfr[n_][1] = *(const i32x4*)(rBx + n_ * 2048);                                    \
    }                                                                                   \
    _Pragma("unroll") for (int m_ = 0; m_ < 2; ++m_) {                                  \
      afr[m_][0] = *(const i32x4*)(rA + m_ * 2048);                                     \
      afr[m_][1] = *(const i32x4*)(rAx + m_ * 2048);                                    \
    }                                                                                   \
    if ((kt) + 1 < NT) {                                                                \
      gl_lds16(aG + 524288 + o1, aDn + 16384);                                          \
      gl_lds16(aG + 524288 + 32768 + o1, aDn + 17408);                                  \
    }                                                                                   \
    __builtin_amdgcn_s_barrier();                                                       \
    asm volatile("s_waitcnt lgkmcnt(0)" ::: "memory");                                  \
    CL8(0, afr);                                                                        \
    __builtin_amdgcn_s_barrier();                                                       \
    /* ---- phase 2: read A mg1 (4); stage B(kt+2) h0 -> cur (free since p1) */         \
    _Pragma("unroll") for (int m_ = 0; m_ < 2; ++m_) {                                  \
      afr[m_][0] = *(const i32x4*)(rA + (2 + m_) * 2048);                               \
      afr[m_][1] = *(const i32x4*)(rAx + (2 + m_) * 2048);                              \
    }                                                                                   \
    if ((kt) + 2 < NT) {                                                                \
      gl_lds16(bG + o2, bDc);                                                           \
      gl_lds16(bG + 32768 + o2, bDc + 1024);                                            \
    }                                                                                   \
    __builtin_amdgcn_s_barrier();                                                       \
    asm volatile("s_waitcnt lgkmcnt(0)" ::: "memory");                                  \
    CL8(2, afr);                                                                        \
    __builtin_amdgcn_s_barrier();                                                       \
    /* ---- phase 3: read A mg2 (4) + A mg3 (4); stage B(kt+2) h1 */                    \
    _Pragma("unroll") for (int m_ = 0; m_ < 2; ++m_) {                                  \
      afr[m_][0]  = *(const i32x4*)(rA + (4 + m_) * 2048);                              \
      afr[m_][1]  = *(const i32x4*)(rAx + (4 + m_) * 2048);                             \
      afr2[m_][0] = *(const i32x4*)(rA + (6 + m_) * 2048);                              \
      afr2[m_][1] = *(const i32x4*)(rAx + (6 + m_) * 2048);                             \
    }                                                                                   \
    if ((kt) + 2 < NT) {                                                                \
      gl_lds16(bG + 524288 + o2, bDc + 16384);                                          \
      gl_lds16(bG + 524288 + 32768 + o2, bDc + 17408);                                  \
    }                                                                                   \
    __builtin_amdgcn_s_barrier();                                                       \
    asm volatile("s_waitcnt lgkmcnt(0)" ::: "memory");                                  \
    CL8(4, afr);                                                                        \
    __builtin_amdgcn_s_barrier();                                                       \
    /* ---- phase 4: stage A(kt+2) h0 -> cur; counted vmcnt(6) */                       \
    if ((kt) + 2 < NT) {                                                                \
      gl_lds16(aG + o2, aDc);                                                           \
      gl_lds16(aG + 32768 + o2, aDc + 1024);                                            \
      asm volatile("s_waitcnt vmcnt(6)" ::: "memory");                                  \
    } else {                                                                            \
      asm volatile("s_waitcnt vmcnt(0)" ::: "memory");                                  \
    }                                                                                   \
    __builtin_amdgcn_s_barrier();                                                       \
    CL8(6, afr2);                                                                       \
    __builtin_amdgcn_s_barrier();                                                       \
  }

__global__ __launch_bounds__(512, 2)
void gemm_i8(const char* __restrict__ xq, const char* __restrict__ Wq,
             const float* __restrict__ sx, const float* __restrict__ scale,
             const float* __restrict__ bias, float* __restrict__ out) {
  __shared__ __align__(16) char sm[131072];
  const int t = threadIdx.x;
  const int w = t >> 6, l = t & 63;
  const int wr = w >> 2, wc = w & 3;          // 2M x 4N waves, 128x64 each
  const int bm = blockIdx.x >> 4, bn = blockIdx.x & 15;
  const int row0 = bm * 256, col0 = bn * 256;

  // --- staging: per-lane pre-swizzled global source (rule #21) ---
  const int srow = l >> 3;                              // row within 8-row group
  const int schunk = ((l & 7) ^ srow) * 16;             // inverse-swizzled 16B chunk
  const char* aG = xq + (size_t)(row0 + w * 16 + srow) * K_IN + schunk;
  const char* bG = Wq + (size_t)(col0 + w * 16 + srow) * K_IN + schunk;
  char* aL0 = sm + w * 2048;                            // + buf*65536 + h*16384
  char* bL0 = sm + 32768 + w * 2048;

  // --- fragment-read base pointers (swizzled), all ds_read = base + imm ---
  const int lrow128 = (l & 15) * 128;
  const int cb0 = (((l >> 4) << 4) ^ ((l & 7) << 4));   // kk=0 colbyte; kk=1: ^64
  const char* rA0  = sm + wr * 16384 + lrow128 + cb0;
  const char* rA0x = sm + wr * 16384 + lrow128 + (cb0 ^ 64);
  const char* rB0  = sm + 32768 + (wc >> 1) * 16384 + (wc & 1) * 8192 + lrow128 + cb0;
  const char* rB0x = sm + 32768 + (wc >> 1) * 16384 + (wc & 1) * 8192 + lrow128 + (cb0 ^ 64);
  const char* rA1  = rA0 + 65536;
  const char* rA1x = rA0x + 65536;
  const char* rB1  = rB0 + 65536;
  const char* rB1x = rB0x + 65536;

  i32x4 acc[8][4];
#pragma unroll
  for (int m = 0; m < 8; ++m)
#pragma unroll
    for (int n = 0; n < 4; ++n) acc[m][n] = (i32x4){0, 0, 0, 0};

  // --- prologue: tile0 fully + tile1 {B0,B1,A0}; wait tile0 (vmcnt 14->6) ---
  gl_lds16(bG, bL0);                 gl_lds16(bG + 32768, bL0 + 1024);          // B0 h0
  gl_lds16(bG + 524288, bL0 + 16384); gl_lds16(bG + 524288 + 32768, bL0 + 17408); // B0 h1
  gl_lds16(aG, aL0);                 gl_lds16(aG + 32768, aL0 + 1024);          // A0 h0
  gl_lds16(aG + 524288, aL0 + 16384); gl_lds16(aG + 524288 + 32768, aL0 + 17408); // A0 h1
  gl_lds16(bG + 128, bL0 + 65536);   gl_lds16(bG + 32768 + 128, bL0 + 66560);   // B1 h0
  gl_lds16(bG + 524288 + 128, bL0 + 81920);                                     // B1 h1
  gl_lds16(bG + 524288 + 32768 + 128, bL0 + 82944);
  gl_lds16(aG + 128, aL0 + 65536);   gl_lds16(aG + 32768 + 128, aL0 + 66560);   // A1 h0
  asm volatile("s_waitcnt vmcnt(6)" ::: "memory");
  __builtin_amdgcn_s_barrier();

  i32x4 bfr[4][2], afr[2][2], afr2[2][2];

  for (int kt = 0; kt < NT; kt += 2) {
    KTBODY(0, kt);
    KTBODY(1, kt + 1);
  }

  // ---- epilogue: C/D col=lane&15, row=(lane>>4)*4+i ; out = acc*sx[r]*sc + bias
  const int orow0 = row0 + wr * 128 + ((l >> 4) << 2);
  const int ocol0 = col0 + wc * 64 + (l & 15);
#pragma unroll
  for (int n = 0; n < 4; ++n) {
    const int col = ocol0 + n * 16;
    const float sc = scale[col];
    const float bi = bias[col];
#pragma unroll
    for (int m = 0; m < 8; ++m) {
      const int r = orow0 + m * 16;
      const float4 sxv = *(const float4*)(sx + r);
      out[(size_t)(r + 0) * N_O + col] = (float)acc[m][n][0] * (sxv.x * sc) + bi;
      out[(size_t)(r + 1) * N_O + col] = (float)acc[m][n][1] * (sxv.y * sc) + bi;
      out[(size_t)(r + 2) * N_O + col] = (float)acc[m][n][2] * (sxv.z * sc) + bi;
      out[(size_t)(r + 3) * N_O + col] = (float)acc[m][n][3] * (sxv.w * sc) + bi;
    }
  }
}

extern "C" void kernel_launch(void* const* d_in, const int* in_sizes, int n_in,
                              void* d_out, int out_size, void* d_ws, size_t ws_size,
                              hipStream_t stream) {
  const float* x    = (const float*)d_in[0];
  const int*   q8   = (const int*)d_in[1];
  const float* s8   = (const float*)d_in[2];
  const int*   q4   = (const int*)d_in[3];
  const float* s4   = (const float*)d_in[4];
  const int*   inv  = (const int*)d_in[5];
  const float* bias = (const float*)d_in[6];
  float* out = (float*)d_out;

  // ws layout: Wq (16 MiB) | scale (16 KiB) | sx (64 KiB) | xq (64 MiB)
  char* ws = (char*)d_ws;
  char*  Wq    = ws;
  float* scale = (float*)(ws + (size_t)N_O * K_IN);
  float* sx    = (float*)(ws + (size_t)N_O * K_IN + 65536);
  char*  xq    = ws + (size_t)N_O * K_IN + 65536 + 65536;

  prep_kernel<<<N_O + M_TOK, 256, 0, stream>>>(x, (const int4*)q8, s8,
                                               (const int4*)q4, s4, inv,
                                               Wq, scale, sx, xq);
  gemm_i8<<<(M_TOK / 256) * (N_O / 256), 512, 0, stream>>>(xq, Wq, sx, scale,
                                                           bias, out);
}